// Round 11
// baseline (95.801 us; speedup 1.0000x reference)
//
#include <hip/hip_runtime.h>
#include <hip/hip_bf16.h>

// MoE layer, MI355X gfx950. B=16, C=64, H=W=128, E=8, TOPK=2.
// out = x + sum_{s in top2} w_s * (W2_e @ gelu((W1_e @ x + b1_e) * k) + b2_e)
// moe_main: BARRIER-FREE. Each wave owns 16 px x all 64 ch; h stays
// wave-private in LDS (2x2KB/wave). 4096 blocks, zero __syncthreads.

#define BB 16
#define CC 64
#define EE 8
#define HWPX 16384

typedef __bf16 bf16x8 __attribute__((ext_vector_type(8)));
typedef float f32x4 __attribute__((ext_vector_type(4)));

__device__ __forceinline__ unsigned packbf2(float lo, float hi) {
    // compiler emits v_cvt_pk_bf16_f32 (RNE)
    __bf16 a = (__bf16)lo, b = (__bf16)hi;
    unsigned short ua = __builtin_bit_cast(unsigned short, a);
    unsigned short ub = __builtin_bit_cast(unsigned short, b);
    return ((unsigned)ub << 16) | (unsigned)ua;
}

// XOR-swizzled dword index into a [16 px][32 dword] wave-private LDS tile.
// 16B chunks XORed by (px&7); same involution on write and read.
__device__ __forceinline__ int swz16(int p, int d) {
    return p * 32 + ((d & ~3) ^ ((p & 7) << 2)) + (d & 3);
}

// ---------------- kernel 1: global avg pool (blocks 0..1023) + W-conv (1024..1151) ----------------
__global__ __launch_bounds__(256) void pool_conv_kernel(
    const float* __restrict__ x, float* __restrict__ pooled,
    const float* __restrict__ W1, const float* __restrict__ W2,
    __bf16* __restrict__ W1b, __bf16* __restrict__ W2b) {
    int blk = blockIdx.x;
    if (blk < BB * CC) {
        const float4* p = (const float4*)(x + (size_t)blk * HWPX);
        float s = 0.f;
        for (int i = threadIdx.x; i < HWPX / 4; i += 256) {
            float4 v = p[i];
            s += (v.x + v.y) + (v.z + v.w);
        }
        #pragma unroll
        for (int off = 32; off > 0; off >>= 1) s += __shfl_down(s, off);
        __shared__ float ls[4];
        if ((threadIdx.x & 63) == 0) ls[threadIdx.x >> 6] = s;
        __syncthreads();
        if (threadIdx.x == 0) pooled[blk] = ((ls[0] + ls[1]) + (ls[2] + ls[3])) * (1.0f / (float)HWPX);
    } else {
        int i = (blk - BB * CC) * 256 + threadIdx.x;  // 0..32767
        W1b[i] = (__bf16)W1[i];
        W2b[i] = (__bf16)W2[i];
    }
}

// ---------------- kernel 2: gate logits + softmax + top2 ----------------
__global__ void gate_kernel(const float* __restrict__ pooled,
                            const float* __restrict__ Wg,
                            const float* __restrict__ bg,
                            int* __restrict__ gidx, float* __restrict__ gw) {
    int b = threadIdx.x;
    if (b >= BB) return;
    float logits[EE];
    #pragma unroll
    for (int e = 0; e < EE; ++e) logits[e] = bg[e];
    for (int c = 0; c < CC; ++c) {
        float pv = pooled[b * CC + c];
        #pragma unroll
        for (int e = 0; e < EE; ++e) logits[e] = fmaf(pv, Wg[c * EE + e], logits[e]);
    }
    float m = logits[0];
    #pragma unroll
    for (int e = 1; e < EE; ++e) m = fmaxf(m, logits[e]);
    float w[EE]; float den = 0.f;
    #pragma unroll
    for (int e = 0; e < EE; ++e) { w[e] = expf(logits[e] - m); den += w[e]; }
    float inv = 1.0f / den;
    #pragma unroll
    for (int e = 0; e < EE; ++e) w[e] *= inv;
    int i0 = 0;
    #pragma unroll
    for (int e = 1; e < EE; ++e) if (w[e] > w[i0]) i0 = e;
    int i1 = -1;
    #pragma unroll
    for (int e = 0; e < EE; ++e) {
        if (e == i0) continue;
        if (i1 < 0 || w[e] > w[i1]) i1 = e;
    }
    gidx[b * 2 + 0] = i0; gidx[b * 2 + 1] = i1;
    gw[b * 2 + 0] = w[i0]; gw[b * 2 + 1] = w[i1];
}

// ---------------- kernel 3: fused top-2 expert MLP + residual (MFMA, barrier-free) ----------------
// Grid: 4096 = 16 batches x 256 tiles (64 px). Block: 256 thr = 4 waves.
// Wave w owns px P0+16w..+15, ALL 64 channels. Lane (g,l15):
//   owns output ch {rt*16+4g+j} x px (base+l15); A-frags rows rt*16+l15.
// h is wave-private: LDS [wave][expert][16px][32dw], no __syncthreads at all.
__global__ __launch_bounds__(256, 4) void moe_main(
    const float* __restrict__ x, const float* __restrict__ kvec,
    const __bf16* __restrict__ W1b, const float* __restrict__ b1,
    const __bf16* __restrict__ W2b, const float* __restrict__ b2,
    const int* __restrict__ gidx, const float* __restrict__ gw,
    float* __restrict__ out) {

    __shared__ unsigned int LH[4][2][16 * 32];   // 16 KiB

    const int blk = blockIdx.x;
    const int b = blk >> 8;            // batch
    const int P0 = (blk & 255) << 6;   // tile base pixel
    const int t = threadIdx.x;
    const int w = t >> 6;              // wave id
    const int l = t & 63;
    const int g = l >> 4;              // 16-lane group
    const int l15 = l & 15;
    const int px = P0 + 16 * w + l15;  // this lane's pixel

    // ---- gate results ----
    const int e0 = __builtin_amdgcn_readfirstlane(gidx[b * 2 + 0]);
    const int e1 = __builtin_amdgcn_readfirstlane(gidx[b * 2 + 1]);
    const float wgt0 = gw[b * 2 + 0];
    const float wgt1 = gw[b * 2 + 1];

    const float* xb = x + b * CC * HWPX + px;   // lane-fixed pixel column
    unsigned int* L0 = &LH[w][0][0];
    unsigned int* L1 = &LH[w][1][0];

    // ---- load this lane's 16 x values (ch rt*16+4g+j), residual + staging ----
    float xc[16];
    #pragma unroll
    for (int rt = 0; rt < 4; ++rt)
        #pragma unroll
        for (int j = 0; j < 4; ++j)
            xc[rt * 4 + j] = xb[(rt * 16 + 4 * g + j) * HWPX];

    // ---- stage x (bf16 pairs) into wave-private LDS, then read B-fragments ----
    #pragma unroll
    for (int rt = 0; rt < 4; ++rt) {
        uint2 pk;
        pk.x = packbf2(xc[rt * 4 + 0], xc[rt * 4 + 1]);
        pk.y = packbf2(xc[rt * 4 + 2], xc[rt * 4 + 3]);
        *(uint2*)&L0[swz16(l15, rt * 8 + 2 * g)] = pk;
    }
    bf16x8 bx0 = *(const bf16x8*)&L0[swz16(l15, 4 * g)];
    bf16x8 bx1 = *(const bf16x8*)&L0[swz16(l15, 16 + 4 * g)];

    // ---- per-lane bias/scale vectors (ch rt*16+4g..+3) ----
    f32x4 b1v0[4], b1v1[4], kk[4], bsum[4];
    #pragma unroll
    for (int rt = 0; rt < 4; ++rt) {
        b1v0[rt] = *(const f32x4*)(b1 + e0 * CC + rt * 16 + 4 * g);
        b1v1[rt] = *(const f32x4*)(b1 + e1 * CC + rt * 16 + 4 * g);
        f32x4 b2v0 = *(const f32x4*)(b2 + e0 * CC + rt * 16 + 4 * g);
        f32x4 b2v1 = *(const f32x4*)(b2 + e1 * CC + rt * 16 + 4 * g);
        kk[rt] = *(const f32x4*)(kvec + b * CC + rt * 16 + 4 * g);
        #pragma unroll
        for (int j = 0; j < 4; ++j) bsum[rt][j] = fmaf(wgt0, b2v0[j], wgt1 * b2v1[j]);
    }

    // gelu sigmoid-form: gelu(t) = t * rcp(1 + exp2(t*(C1 + C2*t^2)))
    const float C1 = -2.302208239f;    // -2*log2(e)*0.7978845608
    const float C2 = -0.1029434f;      // C1 * 0.044715

    bf16x8 a[4][2];                    // A-fragments (rowtile, ks), reused

    // ================= expert 0: GEMM1 + gelu -> L0 (overwrites x; bx in regs) ====
    {
        const __bf16* W1e = W1b + e0 * CC * CC;
        #pragma unroll
        for (int rt = 0; rt < 4; ++rt) {
            a[rt][0] = *(const bf16x8*)(W1e + (rt * 16 + l15) * CC + g * 8);
            a[rt][1] = *(const bf16x8*)(W1e + (rt * 16 + l15) * CC + 32 + g * 8);
        }
        #pragma unroll
        for (int rt = 0; rt < 4; ++rt) {
            f32x4 acc = (f32x4){0.f, 0.f, 0.f, 0.f};
            acc = __builtin_amdgcn_mfma_f32_16x16x32_bf16(a[rt][0], bx0, acc, 0, 0, 0);
            acc = __builtin_amdgcn_mfma_f32_16x16x32_bf16(a[rt][1], bx1, acc, 0, 0, 0);
            float hv[4];
            #pragma unroll
            for (int j = 0; j < 4; ++j) {
                float tt = (acc[j] + b1v0[rt][j]) * kk[rt][j];
                float ex = __builtin_amdgcn_exp2f(tt * fmaf(C2, tt * tt, C1));
                hv[j] = (tt * wgt0) * __builtin_amdgcn_rcpf(ex + 1.f);
            }
            uint2 pk;
            pk.x = packbf2(hv[0], hv[1]);
            pk.y = packbf2(hv[2], hv[3]);
            *(uint2*)&L0[swz16(l15, rt * 8 + 2 * g)] = pk;
        }
    }

    // ================= expert 1: GEMM1 + gelu -> L1 =============================
    {
        const __bf16* W1e = W1b + e1 * CC * CC;
        #pragma unroll
        for (int rt = 0; rt < 4; ++rt) {
            a[rt][0] = *(const bf16x8*)(W1e + (rt * 16 + l15) * CC + g * 8);
            a[rt][1] = *(const bf16x8*)(W1e + (rt * 16 + l15) * CC + 32 + g * 8);
        }
        #pragma unroll
        for (int rt = 0; rt < 4; ++rt) {
            f32x4 acc = (f32x4){0.f, 0.f, 0.f, 0.f};
            acc = __builtin_amdgcn_mfma_f32_16x16x32_bf16(a[rt][0], bx0, acc, 0, 0, 0);
            acc = __builtin_amdgcn_mfma_f32_16x16x32_bf16(a[rt][1], bx1, acc, 0, 0, 0);
            float hv[4];
            #pragma unroll
            for (int j = 0; j < 4; ++j) {
                float tt = (acc[j] + b1v1[rt][j]) * kk[rt][j];
                float ex = __builtin_amdgcn_exp2f(tt * fmaf(C2, tt * tt, C1));
                hv[j] = (tt * wgt1) * __builtin_amdgcn_rcpf(ex + 1.f);
            }
            uint2 pk;
            pk.x = packbf2(hv[0], hv[1]);
            pk.y = packbf2(hv[2], hv[3]);
            *(uint2*)&L1[swz16(l15, rt * 8 + 2 * g)] = pk;
        }
    }

    // ---- read h B-fragments (wave-private; lgkmcnt orders vs writes) ----
    bf16x8 bh00 = *(const bf16x8*)&L0[swz16(l15, 4 * g)];
    bf16x8 bh01 = *(const bf16x8*)&L0[swz16(l15, 16 + 4 * g)];
    bf16x8 bh10 = *(const bf16x8*)&L1[swz16(l15, 4 * g)];
    bf16x8 bh11 = *(const bf16x8*)&L1[swz16(l15, 16 + 4 * g)];

    // ================= GEMM2: acc2 = W2_e0 @ h0 + W2_e1 @ h1 ===================
    f32x4 acc2[4];
    {
        const __bf16* W2e = W2b + e0 * CC * CC;
        #pragma unroll
        for (int rt = 0; rt < 4; ++rt) {
            a[rt][0] = *(const bf16x8*)(W2e + (rt * 16 + l15) * CC + g * 8);
            a[rt][1] = *(const bf16x8*)(W2e + (rt * 16 + l15) * CC + 32 + g * 8);
        }
        #pragma unroll
        for (int rt = 0; rt < 4; ++rt) {
            acc2[rt] = (f32x4){0.f, 0.f, 0.f, 0.f};
            acc2[rt] = __builtin_amdgcn_mfma_f32_16x16x32_bf16(a[rt][0], bh00, acc2[rt], 0, 0, 0);
            acc2[rt] = __builtin_amdgcn_mfma_f32_16x16x32_bf16(a[rt][1], bh01, acc2[rt], 0, 0, 0);
        }
    }
    {
        const __bf16* W2e = W2b + e1 * CC * CC;
        #pragma unroll
        for (int rt = 0; rt < 4; ++rt) {
            a[rt][0] = *(const bf16x8*)(W2e + (rt * 16 + l15) * CC + g * 8);
            a[rt][1] = *(const bf16x8*)(W2e + (rt * 16 + l15) * CC + 32 + g * 8);
        }
        #pragma unroll
        for (int rt = 0; rt < 4; ++rt) {
            acc2[rt] = __builtin_amdgcn_mfma_f32_16x16x32_bf16(a[rt][0], bh10, acc2[rt], 0, 0, 0);
            acc2[rt] = __builtin_amdgcn_mfma_f32_16x16x32_bf16(a[rt][1], bh11, acc2[rt], 0, 0, 0);
        }
    }

    // ---- epilogue: out = x(f32 regs) + acc2 + gated b2 ----
    float* ob = out + b * CC * HWPX + px;
    #pragma unroll
    for (int rt = 0; rt < 4; ++rt)
        #pragma unroll
        for (int j = 0; j < 4; ++j)
            ob[(rt * 16 + 4 * g + j) * HWPX] = xc[rt * 4 + j] + (acc2[rt][j] + bsum[rt][j]);
}

extern "C" void kernel_launch(void* const* d_in, const int* in_sizes, int n_in,
                              void* d_out, int out_size, void* d_ws, size_t ws_size,
                              hipStream_t stream) {
    const float* x  = (const float*)d_in[0];
    const float* k  = (const float*)d_in[1];
    const float* Wg = (const float*)d_in[2];
    const float* bg = (const float*)d_in[3];
    const float* W1 = (const float*)d_in[4];
    const float* b1 = (const float*)d_in[5];
    const float* W2 = (const float*)d_in[6];
    const float* b2 = (const float*)d_in[7];
    float* out = (float*)d_out;

    // workspace layout
    float*  pooled = (float*)d_ws;                          // 4 KiB
    int*    gidx   = (int*)((char*)d_ws + 4096);            // 128 B
    float*  gw     = (float*)((char*)d_ws + 4096 + 128);    // 128 B
    __bf16* W1b    = (__bf16*)((char*)d_ws + 8192);         // 64 KiB
    __bf16* W2b    = (__bf16*)((char*)d_ws + 8192 + 65536); // 64 KiB

    pool_conv_kernel<<<BB * CC + EE * CC * CC / 256, 256, 0, stream>>>(x, pooled, W1, W2, W1b, W2b);
    gate_kernel<<<1, 64, 0, stream>>>(pooled, Wg, bg, gidx, gw);
    moe_main<<<BB * 256, 256, 0, stream>>>(x, k, W1b, b1, W2b, b2, gidx, gw, out);
}